// Round 1
// 3022.896 us; speedup vs baseline: 1.0104x; 1.0104x over previous
//
#include <hip/hip_runtime.h>
#include <hip/hip_bf16.h>
#include <math.h>

#define NS    8
#define NNI   32
#define NCI   128
#define NHH   16
#define NWW   16
#define NCO   128
#define NFF   1152
#define NLL   256
#define LAMV  1152.0f

typedef short s8v __attribute__((ext_vector_type(8)));
typedef float f4v __attribute__((ext_vector_type(4)));

#define AS1 __attribute__((address_space(1)))
#define AS3 __attribute__((address_space(3)))

__device__ __forceinline__ float rdl(float v, int l) {
  return __uint_as_float(__builtin_amdgcn_readlane(__float_as_uint(v), (unsigned)l));
}

// ---------------------------------------------------------------- sqrt_prec table
__global__ void k_sp(const float* __restrict__ lp, float* __restrict__ sp) {
  int t = threadIdx.x;
  if (t < NNI) sp[t] = expf(0.5f * lp[t]);
}

// ---------------------------------------------------------------- build Xu (bf16), z-loop inside
__global__ __launch_bounds__(256) void k_build_Xu(const float* __restrict__ X,
                                                  const float* __restrict__ sp,
                                                  unsigned short* __restrict__ Xu,
                                                  int nz) {
  unsigned idx = blockIdx.x * 256u + threadIdx.x;   // < 1152*8192
  unsigned m = idx & 8191u;
  unsigned f = idx >> 13;
  unsigned n = m >> 8, l = m & 255u, h = l >> 4, w = l & 15u;
  unsigned c = f / 9u, a = f - 9u * c;
  unsigned ki = a / 3u, kj = a - 3u * ki;
  int hi = (int)(h + ki) - 1, wi = (int)(w + kj) - 1;
  bool inb = (hi >= 0 && hi < NHH && wi >= 0 && wi < NWW);
  size_t xoff = (((size_t)n * NCI + c) << 8) + (size_t)(unsigned)(hi * NWW + wi);
  float spn = sp[n];
  for (int z = 0; z < nz; ++z) {
    float v = inb ? X[(size_t)z * 1048576 + xoff] : 0.f;
    __hip_bfloat16 hv = __float2bfloat16(spn * v);
    Xu[(size_t)z * (NFF * 8192) + idx] = *(unsigned short*)&hv;
  }
}

__global__ __launch_bounds__(256) void k_build_B(const float* __restrict__ u,
                                                 const float* __restrict__ sp,
                                                 unsigned short* __restrict__ Bm) {
  unsigned idx = blockIdx.x * 256u + threadIdx.x;   // < 1,048,576
  unsigned m = idx & 8191u;
  unsigned c = idx >> 13;
  unsigned n = m >> 8, l = m & 255u;
  __hip_bfloat16 hv = __float2bfloat16(sp[n] * u[((size_t)n * NCO + c) * NLL + l]);
  Bm[idx] = *(unsigned short*)&hv;
}

__global__ void k_diag_init(float* __restrict__ prec) {
  int s = blockIdx.y;
  int i = blockIdx.x * 256 + threadIdx.x;
  if (i < NFF) prec[(size_t)s * NFF * NFF + (size_t)i * NFF + i] = LAMV;
}

// ---------------------------------------------------------------- MFMA bf16 GEMM, SB s per launch
__global__ __launch_bounds__(256) void k_mfma(const unsigned short* __restrict__ XuBase,
                                              const unsigned short* __restrict__ Bm,
                                              float* __restrict__ prec,
                                              float* __restrict__ XLY,
                                              int kLen, int direct) {
  __shared__ unsigned short As[8192];
  __shared__ unsigned short Bs[8192];
  int z = blockIdx.z;
  const unsigned short* Xu = XuBase + (size_t)z * (NFF * 8192);
  prec += (size_t)z * NFF * NFF;
  XLY += (size_t)z * NFF * NCO;
  int bx = blockIdx.x;
  int row0, col0;
  const unsigned short* Ag;
  const unsigned short* Bg;
  bool isXLX;
  if (bx < 45) {
    int b = 0;
    while ((b + 1) * (b + 2) / 2 <= bx) b++;
    row0 = b * 128;
    col0 = (bx - b * (b + 1) / 2) * 128;
    Bg = Xu + (size_t)col0 * 8192;
    isXLX = true;
  } else {
    row0 = (bx - 45) * 128;
    col0 = 0;
    Bg = Bm;
    isXLX = false;
  }
  Ag = Xu + (size_t)row0 * 8192;

  int t = threadIdx.x;
  int lane = t & 63, w = t >> 6;
  int wm = w & 1, wn = w >> 1;
  int n16 = lane & 15, q = lane >> 4;
  int srow = lane >> 3, sch = lane & 7;

  f4v acc[4][4];
#pragma unroll
  for (int i = 0; i < 4; ++i)
#pragma unroll
    for (int j = 0; j < 4; ++j) acc[i][j] = (f4v)0.f;

  int kBase = blockIdx.y * kLen;
  for (int k0 = kBase; k0 < kBase + kLen; k0 += 64) {
    __syncthreads();
#pragma unroll
    for (int it = 0; it < 4; ++it) {
      int rA = (w * 4 + it) * 8 + srow;
      int cA = (sch - rA) & 7;
      const unsigned short* gpa = Ag + (size_t)rA * 8192 + k0 + cA * 8;
      const unsigned short* gpb = Bg + (size_t)rA * 8192 + k0 + cA * 8;
      __builtin_amdgcn_global_load_lds((AS1 const void*)gpa,
                                       (AS3 void*)&As[(w * 4 + it) * 512], 16, 0, 0);
      __builtin_amdgcn_global_load_lds((AS1 const void*)gpb,
                                       (AS3 void*)&Bs[(w * 4 + it) * 512], 16, 0, 0);
    }
    __syncthreads();
#pragma unroll
    for (int kk = 0; kk < 2; ++kk) {
      s8v af[4], bf[4];
#pragma unroll
      for (int im = 0; im < 4; ++im) {
        int r = wm * 64 + im * 16 + n16;
        int slot = ((kk * 4 + q) + r) & 7;
        af[im] = *(const s8v*)&As[r * 64 + slot * 8];
      }
#pragma unroll
      for (int in = 0; in < 4; ++in) {
        int r = wn * 64 + in * 16 + n16;
        int slot = ((kk * 4 + q) + r) & 7;
        bf[in] = *(const s8v*)&Bs[r * 64 + slot * 8];
      }
#pragma unroll
      for (int im = 0; im < 4; ++im)
#pragma unroll
        for (int in = 0; in < 4; ++in)
          acc[im][in] = __builtin_amdgcn_mfma_f32_16x16x32_bf16(af[im], bf[in], acc[im][in], 0, 0, 0);
    }
  }

#pragma unroll
  for (int im = 0; im < 4; ++im)
#pragma unroll
    for (int in = 0; in < 4; ++in) {
      int gr = row0 + wm * 64 + im * 16 + q * 4;
      int gc = (isXLX ? col0 : 0) + wn * 64 + in * 16 + n16;
      if (direct) {
        if (isXLX) {
#pragma unroll
          for (int tt = 0; tt < 4; ++tt)
            prec[(size_t)(gr + tt) * NFF + gc] =
                acc[im][in][tt] + ((gr + tt) == gc ? LAMV : 0.f);
        } else {
#pragma unroll
          for (int tt = 0; tt < 4; ++tt)
            XLY[(size_t)(gr + tt) * NCO + gc] = acc[im][in][tt];
        }
      } else {
        if (isXLX) {
#pragma unroll
          for (int tt = 0; tt < 4; ++tt)
            atomicAdd(&prec[(size_t)(gr + tt) * NFF + gc], acc[im][in][tt]);
        } else {
#pragma unroll
          for (int tt = 0; tt < 4; ++tt)
            atomicAdd(&XLY[(size_t)(gr + tt) * NCO + gc], acc[im][in][tt]);
        }
      }
    }
}

// ---------------------------------------------------------------- factor block (0,0), 1 wave per s
// lane r holds row r in registers; wave-uniform L[j][k] via v_readlane (pure VALU solve).
__global__ __launch_bounds__(64) void k_fact0(float* __restrict__ P,
                                              float* __restrict__ accum) {
  int s = blockIdx.x;
  int lane = threadIdx.x;
  float* D = P + (size_t)s * NFF * NFF;
  float x[64];
#pragma unroll
  for (int k = 0; k < 64; ++k) x[k] = D[(size_t)lane * NFF + k];
  float ld = 0.f;
#pragma unroll
  for (int k = 0; k < 64; ++k) {
    float dk = sqrtf(rdl(x[k], k));
    float inv = 1.0f / dk;
    ld += logf(dk);
    x[k] = (lane == k) ? dk : ((lane > k) ? x[k] * inv : x[k]);
#pragma unroll
    for (int kk = k + 1; kk < 64; ++kk)
      x[kk] = fmaf(-x[k], rdl(x[k], kk), x[kk]);
  }
  if (lane == 0) atomicAdd(&accum[s * 4 + 2], 2.f * ld);
#pragma unroll
  for (int k = 0; k < 64; ++k) D[(size_t)lane * NFF + k] = x[k];
}

// ---------------------------------------------------------------- panel solve: X * L_pp^T = A(i,p)
// one wave per panel block; row in registers, L column-in-registers + readlane broadcast.
// Writes X to lower (i,p) and transposed copy to upper (p,i).
__global__ __launch_bounds__(64) void k_panel(float* __restrict__ P, int p) {
  int s = blockIdx.y;
  int i = p + 1 + blockIdx.x;
  float* Ps = P + (size_t)s * NFF * NFF;
  const float* Dp = Ps + (size_t)(p * 64) * NFF + p * 64;
  float* Ai = Ps + (size_t)(i * 64) * NFF + p * 64;
  float* At = Ps + (size_t)(p * 64) * NFF + i * 64;
  int lane = threadIdx.x;
  __shared__ float Xs[64][65];
  float Lc[64];                       // Lc[k] = L[k][lane] (column 'lane')
#pragma unroll
  for (int k = 0; k < 64; ++k) Lc[k] = Dp[(size_t)k * NFF + lane];
  for (int r = 0; r < 64; ++r) Xs[r][lane] = Ai[(size_t)r * NFF + lane];
  __syncthreads();
  float x[64];
#pragma unroll
  for (int k = 0; k < 64; ++k) x[k] = Xs[lane][k];
#pragma unroll
  for (int j = 0; j < 64; ++j) {
    float xj = x[j] / rdl(Lc[j], j);
    x[j] = xj;
#pragma unroll
    for (int k = j + 1; k < 64; ++k)
      x[k] = fmaf(-xj, rdl(Lc[k], j), x[k]);
  }
#pragma unroll
  for (int k = 0; k < 64; ++k) Xs[lane][k] = x[k];
  __syncthreads();
  for (int r = 0; r < 64; ++r) Ai[(size_t)r * NFF + lane] = Xs[r][lane];
  for (int r = 0; r < 64; ++r) At[(size_t)r * NFF + lane] = Xs[lane][r];
}

// ---------------------------------------------------------------- trailing update C(i,j) -= P_i P_j^T
// operands read coalesced from the transposed upper copies; register-tiled fp32 GEMM.
// block 0 (i==j==p+1) additionally factors the next diagonal block in-place (wave 0).
__global__ __launch_bounds__(256) void k_trail(float* __restrict__ P,
                                               float* __restrict__ accum, int p) {
  int s = blockIdx.y;
  float* Ps = P + (size_t)s * NFF * NFF;
  int idx = blockIdx.x;
  int b = 0;
  while ((b + 1) * (b + 2) / 2 <= idx) b++;
  int c = idx - b * (b + 1) / 2;
  int i = p + 1 + b, j = p + 1 + c;
  const float* Ui = Ps + (size_t)(p * 64) * NFF + i * 64;   // [k][r]
  const float* Uj = Ps + (size_t)(p * 64) * NFF + j * 64;   // [k][cc]
  float* Cb = Ps + (size_t)(i * 64) * NFF + j * 64;
  __shared__ float Ak[64][68];
  __shared__ float Bk[64][68];
  int t = threadIdx.x, tx = t & 15, ty = t >> 4;
  for (int e = t; e < 1024; e += 256) {
    int k = e >> 4, c4 = (e & 15) * 4;
    *(float4*)&Ak[k][c4] = *(const float4*)(Ui + (size_t)k * NFF + c4);
    *(float4*)&Bk[k][c4] = *(const float4*)(Uj + (size_t)k * NFF + c4);
  }
  __syncthreads();
  float acc[4][4];
#pragma unroll
  for (int a = 0; a < 4; ++a)
#pragma unroll
    for (int b2 = 0; b2 < 4; ++b2) acc[a][b2] = 0.f;
#pragma unroll
  for (int kk = 0; kk < 64; ++kk) {
    float av[4], bv[4];
    *(float4*)&av[0] = *(const float4*)&Ak[kk][ty * 4];
    *(float4*)&bv[0] = *(const float4*)&Bk[kk][tx * 4];
#pragma unroll
    for (int a = 0; a < 4; ++a)
#pragma unroll
      for (int b2 = 0; b2 < 4; ++b2) acc[a][b2] = fmaf(av[a], bv[b2], acc[a][b2]);
  }
  if (!(b == 0 && c == 0)) {
#pragma unroll
    for (int a = 0; a < 4; ++a) {
      float4* cp = (float4*)(Cb + (size_t)(ty * 4 + a) * NFF + tx * 4);
      float4 cv = *cp;
      cv.x -= acc[a][0]; cv.y -= acc[a][1]; cv.z -= acc[a][2]; cv.w -= acc[a][3];
      *cp = cv;
    }
  } else {
    __syncthreads();
#pragma unroll
    for (int a = 0; a < 4; ++a) {
      float4 cv = *(const float4*)(Cb + (size_t)(ty * 4 + a) * NFF + tx * 4);
      cv.x -= acc[a][0]; cv.y -= acc[a][1]; cv.z -= acc[a][2]; cv.w -= acc[a][3];
      *(float4*)&Ak[ty * 4 + a][tx * 4] = cv;
    }
    __syncthreads();
    if (t < 64) {
      int lane = t;
      float x[64];
#pragma unroll
      for (int k = 0; k < 64; ++k) x[k] = Ak[lane][k];
      float ld = 0.f;
#pragma unroll
      for (int k = 0; k < 64; ++k) {
        float dk = sqrtf(rdl(x[k], k));
        float inv = 1.0f / dk;
        ld += logf(dk);
        x[k] = (lane == k) ? dk : ((lane > k) ? x[k] * inv : x[k]);
#pragma unroll
        for (int kk = k + 1; kk < 64; ++kk)
          x[kk] = fmaf(-x[k], rdl(x[k], kk), x[kk]);
      }
      if (lane == 0) atomicAdd(&accum[s * 4 + 2], 2.f * ld);
#pragma unroll
      for (int k = 0; k < 64; ++k) Ak[lane][k] = x[k];
    }
    __syncthreads();
    for (int e = t; e < 1024; e += 256) {
      int r = e >> 4, c4 = (e & 15) * 4;
      *(float4*)(Cb + (size_t)r * NFF + c4) = *(float4*)&Ak[r][c4];
    }
  }
}

// ---------------------------------------------------------------- inverse diag blocks (W = L^{-1})
// lane j holds column j of Linv in registers; L row-in-registers + readlane.
__global__ __launch_bounds__(64) void k_invdiag(const float* __restrict__ P,
                                                float* __restrict__ W) {
  int ib = blockIdx.x, s = blockIdx.y;
  const float* Ps = P + (size_t)s * NFF * NFF + (size_t)(ib * 64) * NFF + ib * 64;
  float* Ws = W + (size_t)s * NFF * NFF + (size_t)(ib * 64) * NFF + ib * 64;
  int lane = threadIdx.x;
  float Lr[64];                       // Lr[m] = L[lane][m] (row 'lane')
#pragma unroll
  for (int m = 0; m < 64; ++m) Lr[m] = Ps[(size_t)lane * NFF + m];
  float x[64];
#pragma unroll
  for (int k = 0; k < 64; ++k) {
    float v = (lane == k) ? 1.f : 0.f;
#pragma unroll
    for (int m = 0; m < k; ++m)
      v = fmaf(-rdl(Lr[m], k), x[m], v);
    x[k] = v / rdl(Lr[k], k);
  }
#pragma unroll
  for (int k = 0; k < 64; ++k) Ws[(size_t)k * NFF + lane] = x[k];
}

// ---------------------------------------------------------------- level-1 pair inverse (fused):
// W[2p+1][2p] = -D2 * L21 * D1, all 64x64, one block per (pair,s)
__global__ __launch_bounds__(256) void k_inv1(const float* __restrict__ P,
                                              float* __restrict__ W) {
  int p = blockIdx.x, s = blockIdx.y;
  int J = 2 * p, I = 2 * p + 1;
  const float* Ps = P + (size_t)s * NFF * NFF;
  float* Ws = W + (size_t)s * NFF * NFF;
  __shared__ float Ak[64][65];   // L21 as [k][i] (from transposed-upper copy)
  __shared__ float Bk[64][65];   // D1 [k][j]
  __shared__ float Dk[64][65];   // D2 as [k][i]
  __shared__ float Tt[64][65];   // T = L21*D1, [k(=i)][j]
  int t = threadIdx.x, tx = t & 15, ty = t >> 4;
  for (int e = t; e < 4096; e += 256) {
    int r = e >> 6, cc = e & 63;
    Ak[r][cc] = Ps[(size_t)(J * 64 + r) * NFF + I * 64 + cc];   // upper copy row
    Bk[r][cc] = Ws[(size_t)(J * 64 + r) * NFF + J * 64 + cc];
  }
  {
    int i = t >> 2;
#pragma unroll
    for (int it = 0; it < 4; ++it) {
      int kq = (t & 3) * 4 + it * 16;
      float4 a = *(const float4*)&Ws[(size_t)(I * 64 + i) * NFF + I * 64 + kq];
      Dk[kq + 0][i] = a.x; Dk[kq + 1][i] = a.y; Dk[kq + 2][i] = a.z; Dk[kq + 3][i] = a.w;
    }
  }
  __syncthreads();
  float acc[4][4];
#pragma unroll
  for (int a = 0; a < 4; ++a)
#pragma unroll
    for (int b = 0; b < 4; ++b) acc[a][b] = 0.f;
#pragma unroll 8
  for (int kk = 0; kk < 64; ++kk) {
    float av[4], bv[4];
#pragma unroll
    for (int a = 0; a < 4; ++a) av[a] = Ak[kk][ty * 4 + a];
#pragma unroll
    for (int b = 0; b < 4; ++b) bv[b] = Bk[kk][tx * 4 + b];
#pragma unroll
    for (int a = 0; a < 4; ++a)
#pragma unroll
      for (int b = 0; b < 4; ++b) acc[a][b] = fmaf(av[a], bv[b], acc[a][b]);
  }
#pragma unroll
  for (int a = 0; a < 4; ++a)
#pragma unroll
    for (int b = 0; b < 4; ++b) Tt[ty * 4 + a][tx * 4 + b] = acc[a][b];
  __syncthreads();
  float a2[4][4];
#pragma unroll
  for (int a = 0; a < 4; ++a)
#pragma unroll
    for (int b = 0; b < 4; ++b) a2[a][b] = 0.f;
#pragma unroll 8
  for (int kk = 0; kk < 64; ++kk) {
    float av[4], bv[4];
#pragma unroll
    for (int a = 0; a < 4; ++a) av[a] = Dk[kk][ty * 4 + a];
#pragma unroll
    for (int b = 0; b < 4; ++b) bv[b] = Tt[kk][tx * 4 + b];
#pragma unroll
    for (int a = 0; a < 4; ++a)
#pragma unroll
      for (int b = 0; b < 4; ++b) a2[a][b] = fmaf(av[a], bv[b], a2[a][b]);
  }
#pragma unroll
  for (int a = 0; a < 4; ++a) {
    float4 o;
    o.x = -a2[a][0]; o.y = -a2[a][1]; o.z = -a2[a][2]; o.w = -a2[a][3];
    *(float4*)&Ws[(size_t)(I * 64 + ty * 4 + a) * NFF + J * 64 + tx * 4] = o;
  }
}

// ---------------------------------------------------------------- level kernel A: T = L21 * W11
// grid (n2, nc, pairs*8); o = (z>>3)*2*n1; tile col c = c0off + blockIdx.y
__global__ __launch_bounds__(256) void k_invA(const float* __restrict__ P,
                                              const float* __restrict__ W,
                                              float* __restrict__ Tb,
                                              int n1, int c0off) {
  int r = blockIdx.x, ccb = blockIdx.y;
  int pq = blockIdx.z >> 3, s = blockIdx.z & 7;
  int o = pq * 2 * n1;
  int n2 = gridDim.x, ldT = gridDim.y * 64;
  int I = o + n1 + r, c = c0off + ccb;
  const float* Ps = P + (size_t)s * NFF * NFF;
  const float* Ws = W + (size_t)s * NFF * NFF;
  float* Ts = Tb + (size_t)s * 147456 + (size_t)pq * (n2 * 64) * ldT;
  __shared__ float Aks[16][68];
  __shared__ float Bks[16][68];
  int t = threadIdx.x, tx = t & 15, ty = t >> 4;
  float acc[4][4];
#pragma unroll
  for (int a = 0; a < 4; ++a)
#pragma unroll
    for (int b = 0; b < 4; ++b) acc[a][b] = 0.f;
  for (int kb = c; kb < n1; ++kb) {
    const float* up = Ps + (size_t)((o + kb) * 64) * NFF + I * 64;     // upper: L[I][kb] as [k][i]
    const float* wp = Ws + (size_t)((o + kb) * 64) * NFF + (o + c) * 64;
    for (int k0 = 0; k0 < 64; k0 += 16) {
      float4 a = *(const float4*)(up + (size_t)(k0 + ty) * NFF + tx * 4);
      float4 b = *(const float4*)(wp + (size_t)(k0 + ty) * NFF + tx * 4);
      __syncthreads();
      *(float4*)&Aks[ty][tx * 4] = a;
      *(float4*)&Bks[ty][tx * 4] = b;
      __syncthreads();
#pragma unroll
      for (int kk = 0; kk < 16; ++kk) {
        float av[4], bv[4];
        *(float4*)&av[0] = *(const float4*)&Aks[kk][ty * 4];
        *(float4*)&bv[0] = *(const float4*)&Bks[kk][tx * 4];
#pragma unroll
        for (int a2 = 0; a2 < 4; ++a2)
#pragma unroll
          for (int b2 = 0; b2 < 4; ++b2) acc[a2][b2] = fmaf(av[a2], bv[b2], acc[a2][b2]);
      }
    }
  }
#pragma unroll
  for (int a = 0; a < 4; ++a) {
    float4 v;
    v.x = acc[a][0]; v.y = acc[a][1]; v.z = acc[a][2]; v.w = acc[a][3];
    *(float4*)(Ts + (size_t)(r * 64 + ty * 4 + a) * ldT + ccb * 64 + tx * 4) = v;
  }
}

// ---------------------------------------------------------------- level kernel B: W21 = -W22 * T
__global__ __launch_bounds__(256) void k_invB(float* __restrict__ W,
                                              const float* __restrict__ Tb,
                                              int n1, int c0off) {
  int r = blockIdx.x, ccb = blockIdx.y;
  int pq = blockIdx.z >> 3, s = blockIdx.z & 7;
  int o = pq * 2 * n1;
  int n2 = gridDim.x, ldT = gridDim.y * 64;
  int I = o + n1 + r, c = c0off + ccb;
  float* Ws = W + (size_t)s * NFF * NFF;
  const float* Ts = Tb + (size_t)s * 147456 + (size_t)pq * (n2 * 64) * ldT;
  __shared__ float Aks[16][68];
  __shared__ float Bks[16][68];
  int t = threadIdx.x, tx = t & 15, ty = t >> 4;
  float acc[4][4];
#pragma unroll
  for (int a = 0; a < 4; ++a)
#pragma unroll
    for (int b = 0; b < 4; ++b) acc[a][b] = 0.f;
  for (int kb = 0; kb <= r; ++kb) {
    const float* ap = Ws + (size_t)(I * 64) * NFF + (o + n1 + kb) * 64;   // W22[r][kb] row-major
    const float* tp = Ts + (size_t)(kb * 64) * ldT + ccb * 64;
    for (int k0 = 0; k0 < 64; k0 += 16) {
      float4 a = *(const float4*)(ap + (size_t)(t >> 2) * NFF + k0 + (t & 3) * 4);
      float4 b = *(const float4*)(tp + (size_t)(k0 + ty) * ldT + tx * 4);
      __syncthreads();
      Aks[(t & 3) * 4 + 0][t >> 2] = a.x;
      Aks[(t & 3) * 4 + 1][t >> 2] = a.y;
      Aks[(t & 3) * 4 + 2][t >> 2] = a.z;
      Aks[(t & 3) * 4 + 3][t >> 2] = a.w;
      *(float4*)&Bks[ty][tx * 4] = b;
      __syncthreads();
#pragma unroll
      for (int kk = 0; kk < 16; ++kk) {
        float av[4], bv[4];
        *(float4*)&av[0] = *(const float4*)&Aks[kk][ty * 4];
        *(float4*)&bv[0] = *(const float4*)&Bks[kk][tx * 4];
#pragma unroll
        for (int a2 = 0; a2 < 4; ++a2)
#pragma unroll
          for (int b2 = 0; b2 < 4; ++b2) acc[a2][b2] = fmaf(av[a2], bv[b2], acc[a2][b2]);
      }
    }
  }
#pragma unroll
  for (int a = 0; a < 4; ++a) {
    float4 v;
    v.x = -acc[a][0]; v.y = -acc[a][1]; v.z = -acc[a][2]; v.w = -acc[a][3];
    *(float4*)&Ws[(size_t)(I * 64 + ty * 4 + a) * NFF + (o + c) * 64 + tx * 4] = v;
  }
}

// ---------------------------------------------------------------- apply: t1R = W*XLY + Z (+sumZ^2)
__global__ __launch_bounds__(256) void k_app1(const float* __restrict__ W,
                                              const float* __restrict__ XLY,
                                              const float* __restrict__ Z,
                                              float* __restrict__ t1R,
                                              float* __restrict__ accum) {
  int rb = blockIdx.x, ch = blockIdx.y, s = blockIdx.z;
  int r0 = rb * 64, c0 = ch * 64;
  const float* Ws = W + (size_t)s * NFF * NFF;
  const float* Ys = XLY + (size_t)s * NFF * NCO;
  const float* Zs = Z + (size_t)s * NFF * NCO;
  float* Os = t1R + (size_t)s * NFF * NCO;
  __shared__ float As_[16][68];
  __shared__ float Bs_[16][68];
  __shared__ float red[256];
  int t = threadIdx.x, tx = t & 15, ty = t >> 4;
  float acc[4][4];
#pragma unroll
  for (int a = 0; a < 4; ++a)
#pragma unroll
    for (int b = 0; b < 4; ++b) acc[a][b] = 0.f;
  int kmax = r0 + 64;
  for (int k0 = 0; k0 < kmax; k0 += 16) {
    float4 a = *(const float4*)(Ws + (size_t)(r0 + (t >> 2)) * NFF + k0 + (t & 3) * 4);
    float4 bb = *(const float4*)(Ys + (size_t)(k0 + (t >> 4)) * NCO + c0 + (t & 15) * 4);
    __syncthreads();
    As_[(t & 3) * 4 + 0][t >> 2] = a.x; As_[(t & 3) * 4 + 1][t >> 2] = a.y;
    As_[(t & 3) * 4 + 2][t >> 2] = a.z; As_[(t & 3) * 4 + 3][t >> 2] = a.w;
    *(float4*)&Bs_[t >> 4][(t & 15) * 4] = bb;
    __syncthreads();
#pragma unroll
    for (int kk = 0; kk < 16; ++kk) {
      float av[4], bv[4];
      *(float4*)&av[0] = *(const float4*)&As_[kk][ty * 4];
      *(float4*)&bv[0] = *(const float4*)&Bs_[kk][tx * 4];
#pragma unroll
      for (int a2 = 0; a2 < 4; ++a2)
#pragma unroll
        for (int b2 = 0; b2 < 4; ++b2) acc[a2][b2] = fmaf(av[a2], bv[b2], acc[a2][b2]);
    }
  }
  float z2 = 0.f;
#pragma unroll
  for (int a2 = 0; a2 < 4; ++a2) {
    int row = r0 + ty * 4 + a2;
    const float* zp = Zs + (size_t)row * NCO + c0 + tx * 4;
    float* op = Os + (size_t)row * NCO + c0 + tx * 4;
    float4 z0 = *(const float4*)zp;
    float4 v0;
    v0.x = acc[a2][0] + z0.x; v0.y = acc[a2][1] + z0.y;
    v0.z = acc[a2][2] + z0.z; v0.w = acc[a2][3] + z0.w;
    z2 += z0.x * z0.x + z0.y * z0.y + z0.z * z0.z + z0.w * z0.w;
    *(float4*)op = v0;
  }
  __syncthreads();
  red[t] = z2;
  __syncthreads();
  for (int o = 128; o > 0; o >>= 1) {
    if (t < o) red[t] += red[t + o];
    __syncthreads();
  }
  if (t == 0) atomicAdd(&accum[s * 4 + 1], red[0]);
}

// ---------------------------------------------------------------- apply: sample = W^T * t1R (+sum S^2)
__global__ __launch_bounds__(256) void k_app2(const float* __restrict__ W,
                                              const float* __restrict__ t1R,
                                              float* __restrict__ sout,
                                              float* __restrict__ accum) {
  int rb = blockIdx.x, ch = blockIdx.y, s = blockIdx.z;
  int r0 = rb * 64, c0 = ch * 64;
  const float* Ws = W + (size_t)s * NFF * NFF;
  const float* Rs = t1R + (size_t)s * NFF * NCO;
  float* Op = sout + (size_t)s * NCO * NFF;
  __shared__ float As_[16][68];
  __shared__ float Bs_[16][68];
  __shared__ float red[256];
  int t = threadIdx.x, tx = t & 15, ty = t >> 4;
  float acc[4][4];
#pragma unroll
  for (int a = 0; a < 4; ++a)
#pragma unroll
    for (int b = 0; b < 4; ++b) acc[a][b] = 0.f;
  for (int k0 = r0; k0 < NFF; k0 += 16) {
    float4 a = *(const float4*)(Ws + (size_t)(k0 + (t >> 4)) * NFF + r0 + (t & 15) * 4);
    float4 bb = *(const float4*)(Rs + (size_t)(k0 + (t >> 4)) * NCO + c0 + (t & 15) * 4);
    __syncthreads();
    *(float4*)&As_[t >> 4][(t & 15) * 4] = a;
    *(float4*)&Bs_[t >> 4][(t & 15) * 4] = bb;
    __syncthreads();
#pragma unroll
    for (int kk = 0; kk < 16; ++kk) {
      float av[4], bv[4];
      *(float4*)&av[0] = *(const float4*)&As_[kk][ty * 4];
      *(float4*)&bv[0] = *(const float4*)&Bs_[kk][tx * 4];
#pragma unroll
      for (int a2 = 0; a2 < 4; ++a2)
#pragma unroll
        for (int b2 = 0; b2 < 4; ++b2) acc[a2][b2] = fmaf(av[a2], bv[b2], acc[a2][b2]);
    }
  }
  float s2 = 0.f;
#pragma unroll
  for (int b2 = 0; b2 < 4; ++b2) {
    int col = c0 + tx * 4 + b2;
    float4 v;
    v.x = acc[0][b2]; v.y = acc[1][b2]; v.z = acc[2][b2]; v.w = acc[3][b2];
    s2 += v.x * v.x + v.y * v.y + v.z * v.z + v.w * v.w;
    *(float4*)(Op + (size_t)col * NFF + r0 + ty * 4) = v;
  }
  __syncthreads();
  red[t] = s2;
  __syncthreads();
  for (int o = 128; o > 0; o >>= 1) {
    if (t < o) red[t] += red[t + o];
    __syncthreads();
  }
  if (t == 0) atomicAdd(&accum[s * 4 + 0], red[0]);
}

__global__ void k_final(const float* __restrict__ accum, float* __restrict__ outLogpq) {
  int s = threadIdx.x;
  if (s < NS) {
    float s2 = accum[s * 4 + 0];
    float z2 = accum[s * 4 + 1];
    float ld = accum[s * 4 + 2];
    float logP = -0.5f * LAMV * s2 + 0.5f * (float)(NCO * NFF) * logf(LAMV);
    float logQ = -0.5f * z2 + 0.5f * (float)NCO * ld;
    outLogpq[s] = logP - logQ;
  }
}

// ---------------------------------------------------------------- launch
extern "C" void kernel_launch(void* const* d_in, const int* in_sizes, int n_in,
                              void* d_out, int out_size, void* d_ws, size_t ws_size,
                              hipStream_t stream) {
  const float* X = (const float*)d_in[0];
  const float* u = (const float*)d_in[1];
  const float* lp = (const float*)d_in[2];
  const float* Z = (const float*)d_in[3];
  float* out = (float*)d_out;

  const size_t XU2 = 18874368;   // 1152*8192*2 (bf16), one s
  const size_t BM2 = 2097152;    // 128*8192*2
  const size_t FF4 = 5308416;    // 1152*1152*4
  const size_t FC4 = 589824;     // 1152*128*4
  const size_t FC = 147456;      // elems
  const size_t FF = 1327104;     // elems
  const size_t XSTR = 1048576;   // X elems per s

  int SB, kslices;
  if (ws_size >= ((size_t)206 << 20))      { SB = 8; kslices = 1; }
  else if (ws_size >= ((size_t)131 << 20)) { SB = 4; kslices = 2; }
  else                                     { SB = 2; kslices = 4; }

  char* ws = (char*)d_ws;
  size_t reg0 = (size_t)SB * XU2 + BM2;
  if (reg0 < 8 * FF4) reg0 = 8 * FF4;      // W aliases region0 after GEMMs
  unsigned short* Xu = (unsigned short*)ws;
  unsigned short* Bm = (unsigned short*)(ws + (size_t)SB * XU2);
  float* W = (float*)ws;
  size_t off = reg0;
  float* prec = (float*)(ws + off); off += 8 * FF4;
  float* XLY = (float*)(ws + off);  off += 8 * FC4;
  float* t1R = (float*)(ws + off);  off += 8 * FC4;   // also level-T scratch
  float* accum = (float*)(ws + off);
  float* sp = accum + 128;

  k_sp<<<1, 64, 0, stream>>>(lp, sp);
  k_build_B<<<4096, 256, 0, stream>>>(u, sp, Bm);
  hipMemsetAsync(accum, 0, 512, stream);
  if (kslices > 1) {
    hipMemsetAsync(prec, 0, 8 * FF4, stream);
    hipMemsetAsync(XLY, 0, 8 * FC4, stream);
    k_diag_init<<<dim3(5, 8), 256, 0, stream>>>(prec);
  }

  for (int pr = 0; pr < 8 / SB; ++pr) {
    k_build_Xu<<<36864, 256, 0, stream>>>(X + (size_t)pr * SB * XSTR, sp, Xu, SB);
    k_mfma<<<dim3(54, kslices, SB), 256, 0, stream>>>(Xu, Bm,
                                                      prec + (size_t)pr * SB * FF,
                                                      XLY + (size_t)pr * SB * FC,
                                                      8192 / kslices, kslices == 1 ? 1 : 0);
  }

  // blocked Cholesky: factor(0), then per step: panel solves (once each) + GEMM trailing
  // (next diag factor fused into trailing block 0)
  k_fact0<<<8, 64, 0, stream>>>(prec, accum);
  for (int p = 0; p < 17; ++p) {
    int m = 17 - p;
    k_panel<<<dim3(m, 8), 64, 0, stream>>>(prec, p);
    k_trail<<<dim3(m * (m + 1) / 2, 8), 256, 0, stream>>>(prec, accum, p);
  }

  // W = L^{-1} via recursive block doubling
  k_invdiag<<<dim3(18, 8), 64, 0, stream>>>(prec, W);
  k_inv1<<<dim3(9, 8), 256, 0, stream>>>(prec, W);                       // pairs of 64
  k_invA<<<dim3(2, 2, 32), 256, 0, stream>>>(prec, W, t1R, 2, 0);        // n=128 pairs
  k_invB<<<dim3(2, 2, 32), 256, 0, stream>>>(W, t1R, 2, 0);
  k_invA<<<dim3(4, 4, 16), 256, 0, stream>>>(prec, W, t1R, 4, 0);        // n=256 pairs
  k_invB<<<dim3(4, 4, 16), 256, 0, stream>>>(W, t1R, 4, 0);
  k_invA<<<dim3(8, 4, 8), 256, 0, stream>>>(prec, W, t1R, 8, 0);         // n=512, cols 0-3
  k_invB<<<dim3(8, 4, 8), 256, 0, stream>>>(W, t1R, 8, 0);
  k_invA<<<dim3(8, 4, 8), 256, 0, stream>>>(prec, W, t1R, 8, 4);         // n=512, cols 4-7
  k_invB<<<dim3(8, 4, 8), 256, 0, stream>>>(W, t1R, 8, 4);
  k_invA<<<dim3(2, 16, 8), 256, 0, stream>>>(prec, W, t1R, 16, 0);       // (1024,128) final
  k_invB<<<dim3(2, 16, 8), 256, 0, stream>>>(W, t1R, 16, 0);

  // sample = W^T (W XLY + Z); fused reductions
  k_app1<<<dim3(18, 2, 8), 256, 0, stream>>>(W, XLY, Z, t1R, accum);
  k_app2<<<dim3(18, 2, 8), 256, 0, stream>>>(W, t1R, out, accum);
  k_final<<<1, 64, 0, stream>>>(accum, out + (size_t)NS * FC);
}